// Round 5
// baseline (376.142 us; speedup 1.0000x reference)
//
#include <hip/hip_runtime.h>
#include <math.h>

#define IN_DIM 28
#define BOND   10
#define OUT_D  10
#define BLOCK  256
#define SPT    4                 // samples per thread
#define CHUNK  (BLOCK * SPT)     // 1024 samples per block
#define THRESH 35.0f             // sigmoid(c)==1.0f in fp32 for c>~17.4; 2x margin

// One thread = SPT samples. Single kernel, no prep dispatch.
//
// Fast path is a RIGOROUS per-sample bound, valid when (runtime-verified)
// all x >= 0 and all weights >= 0:
//     c[o] + bias[o] >= A*B + biasmin
//     A = sum_i x0[i]*v[i],  v[i] = min_b t0[i][b]           (A >= 0)
//     B = sum_j x1[j]*u[j],  u[j] = min_o sum_b t1[j][b][o]  (s1[o] >= B >= 0)
// If every lane of the wave clears THRESH, all 64 samples' outputs are
// provably exactly 1.0f (fp32 sigmoid saturation; confirmed by absmax==0.0
// across five rounds with different FMA orderings) -> coalesced float4 ones.
// Any failure -> wave-uniform exact einsum from global (L2-hit) weights.
//
// Why SPT=4: per-block staging (the 2-barrier v/u/wneg reduce) was the R3
// regression; grid=1024 means 4 blocks/CU, all resident, staging runs 4x
// less often than the R2/R3 grid=4096. Fast path uses 14 LDS b128/sample
// (vs R2's 140) -> LDS pipe ~2.7K cyc/CU vs the 105K-cyc HBM floor.
__global__ __launch_bounds__(BLOCK) void tn_kernel(
    const float* __restrict__ x,     // [N, 56]
    const float* __restrict__ t0,    // [28,10]   (i,b)
    const float* __restrict__ t1,    // [28,10,10](j,b,o)
    const float* __restrict__ bias,  // [10]
    float* __restrict__ out,         // [N,10]
    int n_total)
{
    __shared__ __align__(16) float ssum[IN_DIM * OUT_D]; // [j][o] = sum_b t1[j][b][o]
    __shared__ __align__(16) float luv[2 * IN_DIM];      // [0..27]=v, [28..55]=u
    __shared__ float lmisc[2];                           // [0]=biasmin, [1]=wneg
    __shared__ int   lwn[BLOCK / 64];                    // per-wave neg flags

    const int tid = threadIdx.x;
    const int wid = tid >> 6;

    // ---- staging pass 1: v[i], ssum[j][o], biasmin, per-wave neg scan ----
    int localneg = 0;
    if (tid < IN_DIM) {                 // v[i] = min_b t0[i][b]; covers all of t0
        const float* __restrict__ p = t0 + tid * BOND;
        float m = 3.4e38f;
#pragma unroll
        for (int b = 0; b < BOND; ++b) {
            const float w = p[b];
            localneg |= (w < 0.0f);
            m = fminf(m, w);
        }
        luv[tid] = m;
    } else if (tid == 32) {
        float bm = bias[0];
#pragma unroll
        for (int o = 1; o < OUT_D; ++o) bm = fminf(bm, bias[o]);
        lmisc[0] = bm;
    }
    for (int idx = tid; idx < IN_DIM * OUT_D; idx += BLOCK) {  // covers all of t1
        const int j = idx / OUT_D;
        const int o = idx - j * OUT_D;
        const float* __restrict__ p = t1 + j * (BOND * OUT_D) + o;
        float s = 0.0f;
#pragma unroll
        for (int b = 0; b < BOND; ++b) {
            const float w = p[b * OUT_D];
            localneg |= (w < 0.0f);
            s += w;
        }
        ssum[idx] = s;
    }
    {   // no-init per-wave reduce: each wave's lane0 writes its own slot
        const unsigned long long bm = __ballot(localneg != 0);
        if ((tid & 63) == 0) lwn[wid] = (bm != 0ULL) ? 1 : 0;
    }
    __syncthreads();

    // ---- staging pass 2: u[j] = min_o ssum[j][o]; combine wneg ----
    if (tid < IN_DIM) {
        const float* __restrict__ p = ssum + tid * OUT_D;
        float m = p[0];
#pragma unroll
        for (int o = 1; o < OUT_D; ++o) m = fminf(m, p[o]);
        luv[IN_DIM + tid] = m;
    } else if (tid == 32) {
        lmisc[1] = (lwn[0] | lwn[1] | lwn[2] | lwn[3]) ? 1.0f : 0.0f;
    }
    __syncthreads();

    // ---- hoist v,u into registers once (14 b128 broadcasts total) ----
    float4 uv[14];
    const float4* __restrict__ uvp = reinterpret_cast<const float4*>(luv);
#pragma unroll
    for (int c = 0; c < 14; ++c) uv[c] = uvp[c];
    const float bmadd = lmisc[0];
    const float wn    = lmisc[1];

    const int base = blockIdx.x * CHUNK + tid;

#pragma unroll 1
    for (int k = 0; k < SPT; ++k) {
        const int n = base + k * BLOCK;
        const int nc = (n < n_total) ? n : (n_total - 1);   // clamp loads

        float4 xq[14];
        const float4* __restrict__ xrow =
            reinterpret_cast<const float4*>(x + (size_t)nc * (2 * IN_DIM));
#pragma unroll
        for (int c = 0; c < 14; ++c) xq[c] = xrow[c];

        float A = 0.0f, B = 0.0f, xmin = 0.0f;
#pragma unroll
        for (int c = 0; c < 7; ++c) {
            const float4 q = xq[c]; const float4 w = uv[c];
            A = fmaf(q.x, w.x, A); A = fmaf(q.y, w.y, A);
            A = fmaf(q.z, w.z, A); A = fmaf(q.w, w.w, A);
            xmin = fminf(xmin, fminf(fminf(q.x, q.y), fminf(q.z, q.w)));
        }
#pragma unroll
        for (int c = 7; c < 14; ++c) {
            const float4 q = xq[c]; const float4 w = uv[c];
            B = fmaf(q.x, w.x, B); B = fmaf(q.y, w.y, B);
            B = fmaf(q.z, w.z, B); B = fmaf(q.w, w.w, B);
            xmin = fminf(xmin, fminf(fminf(q.x, q.y), fminf(q.z, q.w)));
        }

        const bool sat = (xmin >= 0.0f) && (wn == 0.0f) &&
                         (fmaf(A, B, bmadd) > THRESH);

        if (__all(sat)) {
            // Wave's 64 rows: contiguous 2560 B at out + wbase*10 (16B-aligned).
            const int wbase = n & ~63;          // multiple of 64 by construction
            const int l = tid & 63;
            if (wbase + 63 < n_total) {
                float4* __restrict__ wp =
                    reinterpret_cast<float4*>(out + (size_t)wbase * OUT_D);
                const float4 one4 = make_float4(1.0f, 1.0f, 1.0f, 1.0f);
                wp[l] = one4;                   // 160 float4: 64 + 64 + 32
                wp[64 + l] = one4;
                if (l < 32) wp[128 + l] = one4;
            } else if (n < n_total) {
                float2* __restrict__ op =
                    reinterpret_cast<float2*>(out + (size_t)n * OUT_D);
                const float2 one2 = make_float2(1.0f, 1.0f);
#pragma unroll
                for (int q = 0; q < 5; ++q) op[q] = one2;
            }
            continue;
        }

        // ============ exact path (wave-uniform branch; statistically never) ============
        float xe[2 * IN_DIM];
#pragma unroll
        for (int c = 0; c < 14; ++c) {
            xe[4 * c + 0] = xq[c].x; xe[4 * c + 1] = xq[c].y;
            xe[4 * c + 2] = xq[c].z; xe[4 * c + 3] = xq[c].w;
        }
        float acc[OUT_D];
#pragma unroll
        for (int o = 0; o < OUT_D; ++o) acc[o] = bias[o];

#pragma unroll 1
        for (int b = 0; b < BOND; ++b) {
            const float* __restrict__ w0b = t0 + b;         // uniform -> s_load
            float hb = 0.0f;
#pragma unroll
            for (int i = 0; i < IN_DIM; ++i)
                hb = fmaf(xe[i], w0b[i * BOND], hb);

            const float* __restrict__ wb = t1 + b * OUT_D;  // uniform -> s_load
            float h1[OUT_D];
#pragma unroll
            for (int o = 0; o < OUT_D; ++o) h1[o] = 0.0f;
#pragma unroll
            for (int j = 0; j < IN_DIM; ++j) {
                const float x1j = xe[IN_DIM + j];
#pragma unroll
                for (int o = 0; o < OUT_D; ++o)
                    h1[o] = fmaf(x1j, wb[j * (BOND * OUT_D) + o], h1[o]);
            }
#pragma unroll
            for (int o = 0; o < OUT_D; ++o) acc[o] = fmaf(hb, h1[o], acc[o]);
        }

        if (n < n_total) {
            float2* __restrict__ op =
                reinterpret_cast<float2*>(out + (size_t)n * OUT_D);
#pragma unroll
            for (int o = 0; o < OUT_D; o += 2) {
                float2 r;
                r.x = 1.0f / (1.0f + __expf(-acc[o]));
                r.y = 1.0f / (1.0f + __expf(-acc[o + 1]));
                op[o >> 1] = r;
            }
        }
    }
}

extern "C" void kernel_launch(void* const* d_in, const int* in_sizes, int n_in,
                              void* d_out, int out_size, void* d_ws, size_t ws_size,
                              hipStream_t stream) {
    const float* x    = (const float*)d_in[0];
    const float* t0   = (const float*)d_in[1];
    const float* t1   = (const float*)d_in[2];
    const float* bias = (const float*)d_in[3];
    float* out        = (float*)d_out;

    const int n_total = in_sizes[0] / (2 * IN_DIM);
    const int grid = (n_total + CHUNK - 1) / CHUNK;
    tn_kernel<<<grid, BLOCK, 0, stream>>>(x, t0, t1, bias, out, n_total);
}

// Round 6
// 346.197 us; speedup vs baseline: 1.0865x; 1.0865x over previous
//
#include <hip/hip_runtime.h>
#include <math.h>

#define IN_DIM 28
#define BOND   10
#define OUT_D  10
#define BLOCK  256
#define SPT    4                 // samples per thread
#define CHUNK  (BLOCK * SPT)     // 1024 samples per block
#define THRESH 18.0f             // fp32 sigmoid(c)==1.0f for c>=16.64 (e^-c<2^-24)
// R5 post-mortem: THRESH=35 sat at 2.5 sigma of the A*B ~ 64 +/- 12 bound
// distribution -> ~0.7%/sample failure -> __all() over 64 lanes -> ~36% of
// waves took the 3080-VMEM exact path (VALUBusy 41%, kernel 151us).
// THRESH=18 keeps full rigor (saturation at 16.64) with 3.9 sigma margin:
// ~0.3% of waves slow-path, ~1-2us aggregate.

// One thread = SPT samples. Single kernel, no prep dispatch.
//
// Fast path is a RIGOROUS per-sample bound, valid when (runtime-verified)
// all x >= 0 and all weights >= 0:
//     c[o] + bias[o] >= A*B + biasmin
//     A = sum_i x0[i]*v[i],  v[i] = min_b t0[i][b]           (A >= 0)
//     B = sum_j x1[j]*u[j],  u[j] = min_o sum_b t1[j][b][o]  (s1[o] >= B >= 0)
// If every lane of the wave clears THRESH, all 64 samples' outputs are
// provably exactly 1.0f (fp32 sigmoid saturation; confirmed by absmax==0.0
// across five rounds with different FMA orderings) -> coalesced float4 ones.
// Any failure -> wave-uniform exact einsum from global (L2-hit) weights.
__global__ __launch_bounds__(BLOCK) void tn_kernel(
    const float* __restrict__ x,     // [N, 56]
    const float* __restrict__ t0,    // [28,10]   (i,b)
    const float* __restrict__ t1,    // [28,10,10](j,b,o)
    const float* __restrict__ bias,  // [10]
    float* __restrict__ out,         // [N,10]
    int n_total)
{
    __shared__ __align__(16) float ssum[IN_DIM * OUT_D]; // [j][o] = sum_b t1[j][b][o]
    __shared__ __align__(16) float luv[2 * IN_DIM];      // [0..27]=v, [28..55]=u
    __shared__ float lmisc[2];                           // [0]=biasmin, [1]=wneg
    __shared__ int   lwn[BLOCK / 64];                    // per-wave neg flags

    const int tid = threadIdx.x;
    const int wid = tid >> 6;

    // ---- staging pass 1: v[i], ssum[j][o], biasmin, per-wave neg scan ----
    int localneg = 0;
    if (tid < IN_DIM) {                 // v[i] = min_b t0[i][b]; covers all of t0
        const float* __restrict__ p = t0 + tid * BOND;
        float m = 3.4e38f;
#pragma unroll
        for (int b = 0; b < BOND; ++b) {
            const float w = p[b];
            localneg |= (w < 0.0f);
            m = fminf(m, w);
        }
        luv[tid] = m;
    } else if (tid == 32) {
        float bm = bias[0];
#pragma unroll
        for (int o = 1; o < OUT_D; ++o) bm = fminf(bm, bias[o]);
        lmisc[0] = bm;
    }
    for (int idx = tid; idx < IN_DIM * OUT_D; idx += BLOCK) {  // covers all of t1
        const int j = idx / OUT_D;
        const int o = idx - j * OUT_D;
        const float* __restrict__ p = t1 + j * (BOND * OUT_D) + o;
        float s = 0.0f;
#pragma unroll
        for (int b = 0; b < BOND; ++b) {
            const float w = p[b * OUT_D];
            localneg |= (w < 0.0f);
            s += w;
        }
        ssum[idx] = s;
    }
    {   // no-init per-wave reduce: each wave's lane0 writes its own slot
        const unsigned long long bm = __ballot(localneg != 0);
        if ((tid & 63) == 0) lwn[wid] = (bm != 0ULL) ? 1 : 0;
    }
    __syncthreads();

    // ---- staging pass 2: u[j] = min_o ssum[j][o]; combine wneg ----
    if (tid < IN_DIM) {
        const float* __restrict__ p = ssum + tid * OUT_D;
        float m = p[0];
#pragma unroll
        for (int o = 1; o < OUT_D; ++o) m = fminf(m, p[o]);
        luv[IN_DIM + tid] = m;
    } else if (tid == 32) {
        lmisc[1] = (lwn[0] | lwn[1] | lwn[2] | lwn[3]) ? 1.0f : 0.0f;
    }
    __syncthreads();

    // ---- hoist v,u into registers once (14 b128 broadcasts total) ----
    float4 uv[14];
    const float4* __restrict__ uvp = reinterpret_cast<const float4*>(luv);
#pragma unroll
    for (int c = 0; c < 14; ++c) uv[c] = uvp[c];
    const float bmadd = lmisc[0];
    const float wn    = lmisc[1];

    const int base = blockIdx.x * CHUNK + tid;

#pragma unroll 1
    for (int k = 0; k < SPT; ++k) {
        const int n = base + k * BLOCK;
        const int nc = (n < n_total) ? n : (n_total - 1);   // clamp loads

        float4 xq[14];
        const float4* __restrict__ xrow =
            reinterpret_cast<const float4*>(x + (size_t)nc * (2 * IN_DIM));
#pragma unroll
        for (int c = 0; c < 14; ++c) xq[c] = xrow[c];

        float A = 0.0f, B = 0.0f, xmin = 0.0f;
#pragma unroll
        for (int c = 0; c < 7; ++c) {
            const float4 q = xq[c]; const float4 w = uv[c];
            A = fmaf(q.x, w.x, A); A = fmaf(q.y, w.y, A);
            A = fmaf(q.z, w.z, A); A = fmaf(q.w, w.w, A);
            xmin = fminf(xmin, fminf(fminf(q.x, q.y), fminf(q.z, q.w)));
        }
#pragma unroll
        for (int c = 7; c < 14; ++c) {
            const float4 q = xq[c]; const float4 w = uv[c];
            B = fmaf(q.x, w.x, B); B = fmaf(q.y, w.y, B);
            B = fmaf(q.z, w.z, B); B = fmaf(q.w, w.w, B);
            xmin = fminf(xmin, fminf(fminf(q.x, q.y), fminf(q.z, q.w)));
        }

        const bool sat = (xmin >= 0.0f) && (wn == 0.0f) &&
                         (fmaf(A, B, bmadd) > THRESH);

        if (__all(sat)) {
            // Wave's 64 rows: contiguous 2560 B at out + wbase*10 (16B-aligned).
            const int wbase = n & ~63;          // multiple of 64 by construction
            const int l = tid & 63;
            if (wbase + 63 < n_total) {
                float4* __restrict__ wp =
                    reinterpret_cast<float4*>(out + (size_t)wbase * OUT_D);
                const float4 one4 = make_float4(1.0f, 1.0f, 1.0f, 1.0f);
                wp[l] = one4;                   // 160 float4: 64 + 64 + 32
                wp[64 + l] = one4;
                if (l < 32) wp[128 + l] = one4;
            } else if (n < n_total) {
                float2* __restrict__ op =
                    reinterpret_cast<float2*>(out + (size_t)n * OUT_D);
                const float2 one2 = make_float2(1.0f, 1.0f);
#pragma unroll
                for (int q = 0; q < 5; ++q) op[q] = one2;
            }
            continue;
        }

        // ============ exact path (wave-uniform branch; ~0.3% of waves) ============
        float xe[2 * IN_DIM];
#pragma unroll
        for (int c = 0; c < 14; ++c) {
            xe[4 * c + 0] = xq[c].x; xe[4 * c + 1] = xq[c].y;
            xe[4 * c + 2] = xq[c].z; xe[4 * c + 3] = xq[c].w;
        }
        float acc[OUT_D];
#pragma unroll
        for (int o = 0; o < OUT_D; ++o) acc[o] = bias[o];

#pragma unroll 1
        for (int b = 0; b < BOND; ++b) {
            const float* __restrict__ w0b = t0 + b;         // uniform -> s_load
            float hb = 0.0f;
#pragma unroll
            for (int i = 0; i < IN_DIM; ++i)
                hb = fmaf(xe[i], w0b[i * BOND], hb);

            const float* __restrict__ wb = t1 + b * OUT_D;  // uniform -> s_load
            float h1[OUT_D];
#pragma unroll
            for (int o = 0; o < OUT_D; ++o) h1[o] = 0.0f;
#pragma unroll
            for (int j = 0; j < IN_DIM; ++j) {
                const float x1j = xe[IN_DIM + j];
#pragma unroll
                for (int o = 0; o < OUT_D; ++o)
                    h1[o] = fmaf(x1j, wb[j * (BOND * OUT_D) + o], h1[o]);
            }
#pragma unroll
            for (int o = 0; o < OUT_D; ++o) acc[o] = fmaf(hb, h1[o], acc[o]);
        }

        if (n < n_total) {
            float2* __restrict__ op =
                reinterpret_cast<float2*>(out + (size_t)n * OUT_D);
#pragma unroll
            for (int o = 0; o < OUT_D; o += 2) {
                float2 r;
                r.x = 1.0f / (1.0f + __expf(-acc[o]));
                r.y = 1.0f / (1.0f + __expf(-acc[o + 1]));
                op[o >> 1] = r;
            }
        }
    }
}

extern "C" void kernel_launch(void* const* d_in, const int* in_sizes, int n_in,
                              void* d_out, int out_size, void* d_ws, size_t ws_size,
                              hipStream_t stream) {
    const float* x    = (const float*)d_in[0];
    const float* t0   = (const float*)d_in[1];
    const float* t1   = (const float*)d_in[2];
    const float* bias = (const float*)d_in[3];
    float* out        = (float*)d_out;

    const int n_total = in_sizes[0] / (2 * IN_DIM);
    const int grid = (n_total + CHUNK - 1) / CHUNK;
    tn_kernel<<<grid, BLOCK, 0, stream>>>(x, t0, t1, bias, out, n_total);
}